// Round 2
// 383.432 us; speedup vs baseline: 81.8976x; 81.8976x over previous
//
#include <hip/hip_runtime.h>
#include <math.h>

#define TOPK 100
#define HW 65536                   // 256*256
#define SLICE_STRIDE (7*HW)        // 458752
#define NBATCH 32
#define NBOX 200
#define HM (3*HW)                  // 196608 heatmap elems per slice
#define CAP 4096                   // candidate buffer (expected ~113 candidates)

// Order-preserving float->uint key: f1 > f2  <=>  key(f1) > key(f2)
__device__ __forceinline__ unsigned fkey(float f) {
    unsigned u = __float_as_uint(f);
    return (u & 0x80000000u) ? ~u : (u | 0x80000000u);
}

// ---------------------------------------------------------------------------
// Kernel 1: exact top-100 per slice via histogram threshold + bitonic sort.
// One block per slice (64 blocks, 1024 threads). Selection order is identical
// to the round-0 verified kernel (absmax 0.0): descending raw logit, ties ->
// lowest index (64-bit key = (valkey << 32) | ~idx; all keys distinct).
// Results land in the output buffer's own per-batch regions (boxes/cls/
// scores), which kernel 2 then reads — no workspace needed.
// ---------------------------------------------------------------------------
__global__ __launch_bounds__(1024) void ktopk(const float* __restrict__ x,
                                              float* __restrict__ out) {
    __shared__ unsigned hist[4096];                 // 16 KB
    __shared__ unsigned long long cand[CAP];        // 32 KB (aliased as tmp)
    __shared__ int shB, shB2;
    __shared__ unsigned shAbove, shNcand, shNc;

    const int slice = blockIdx.x;
    const int b = slice >> 1, s = slice & 1;
    const int t = threadIdx.x;
    const float* xb = x + (size_t)slice * SLICE_STRIDE;
    const float4* xb4 = (const float4*)xb;
    const int N4 = HM / 4;                          // 49152

    if (t == 0) { shB = 0; shB2 = 0; shAbove = 0u; shNcand = 0u; shNc = 0u; }
    for (int i = t; i < 4096; i += 1024) hist[i] = 0u;
    __syncthreads();

    // ---- pass 1: histogram of top-12 key bits ----
    for (int i = t; i < N4; i += 1024) {
        float4 v = xb4[i];
        float a[4] = {v.x, v.y, v.z, v.w};
        #pragma unroll
        for (int c_ = 0; c_ < 4; ++c_) {
            unsigned vk = fkey(a[c_]);
            atomicAdd(&hist[vk >> 20], 1u);
        }
    }
    __syncthreads();

    // ---- parallel suffix-sum (Hillis-Steele ping-pong, 12 passes) ----
    {
        unsigned* tmp = (unsigned*)cand;
        unsigned* src = hist;
        unsigned* dst = tmp;
        for (int d = 1; d < 4096; d <<= 1) {
            for (int i = t; i < 4096; i += 1024) {
                unsigned v = src[i];
                if (i + d < 4096) v += src[i + d];
                dst[i] = v;
            }
            __syncthreads();
            unsigned* sw = src; src = dst; dst = sw;
        }
        // boundary bin B: suffix[B] >= 100, suffix[B+1] < 100 (unique; always
        // exists because suffix[0] = HM >= 100 and suffix beyond 4095 is 0)
        for (int i = t; i < 4096; i += 1024) {
            unsigned sb = src[i];
            unsigned sn = (i < 4095) ? src[i + 1] : 0u;
            if (sb >= TOPK && sn < TOPK) { shB = i; shAbove = sn; shNcand = sb; }
        }
        __syncthreads();
    }

    // ---- rare exact-refinement path (only if >CAP ties in boundary bin) ----
    const bool refine = (shNcand > CAP);
    if (refine) {
        for (int i = t; i < 4096; i += 1024) hist[i] = 0u;
        __syncthreads();
        const unsigned Bv = (unsigned)shB;
        for (int i = t; i < N4; i += 1024) {
            float4 v = xb4[i];
            float a[4] = {v.x, v.y, v.z, v.w};
            #pragma unroll
            for (int c_ = 0; c_ < 4; ++c_) {
                unsigned vk = fkey(a[c_]);
                if ((vk >> 20) == Bv) atomicAdd(&hist[(vk >> 8) & 0xFFFu], 1u);
            }
        }
        __syncthreads();
        if (t == 0) {
            unsigned need = TOPK - shAbove, cum = 0u;
            int b2 = 4095;
            for (; b2 >= 0; --b2) { cum += hist[b2]; if (cum >= need) break; }
            shB2 = (b2 < 0) ? 0 : b2;
            shNcand = shAbove + cum;
        }
        __syncthreads();
    }

    // ---- pass 2: collect candidate 64-bit keys ----
    {
        const unsigned Bv = (unsigned)shB;
        const unsigned B2v = refine ? (unsigned)shB2 : 0u;
        for (int i = t; i < N4; i += 1024) {
            float4 v = xb4[i];
            float a[4] = {v.x, v.y, v.z, v.w};
            #pragma unroll
            for (int c_ = 0; c_ < 4; ++c_) {
                unsigned vk = fkey(a[c_]);
                unsigned bin = vk >> 20;
                bool q = refine ? (bin > Bv || (bin == Bv && ((vk >> 8) & 0xFFFu) >= B2v))
                                : (bin >= Bv);
                if (q) {
                    unsigned pos = atomicAdd(&shNc, 1u);
                    if (pos < CAP)
                        cand[pos] = ((unsigned long long)vk << 32) |
                                    (unsigned)~(unsigned)(i * 4 + c_);
                }
            }
        }
        __syncthreads();
    }

    unsigned nc = shNc; if (nc > CAP) nc = CAP;     // nc >= 100 by construction

    // ---- pad to pow2 and bitonic sort descending ----
    int P = 128; while (P < (int)nc) P <<= 1;       // <= 4096
    for (int i = (int)nc + t; i < P; i += 1024) cand[i] = 0ull;  // pads sort last
    __syncthreads();
    for (int k = 2; k <= P; k <<= 1) {
        for (int j = k >> 1; j > 0; j >>= 1) {
            for (int i = t; i < P; i += 1024) {
                int ixj = i ^ j;
                if (ixj > i) {
                    unsigned long long a = cand[i], c2 = cand[ixj];
                    bool sw = ((i & k) == 0) ? (a < c2) : (a > c2);
                    if (sw) { cand[i] = c2; cand[ixj] = a; }
                }
            }
            __syncthreads();
        }
    }

    // ---- decode ranks 0..99 (formulas verbatim from verified kernel) ----
    if (t < TOPK) {
        unsigned long long K = cand[t];
        unsigned vk = (unsigned)(K >> 32);
        unsigned idx = ~((unsigned)K);
        unsigned u = (vk & 0x80000000u) ? (vk & 0x7FFFFFFFu) : ~vk;
        float z = __uint_as_float(u);               // exact original logit
        int c = (int)(idx >> 16);                   // HW == 2^16
        int rem = (int)(idx & 0xFFFFu);
        float ysf = (float)(rem >> 8);
        float xsf = (float)(rem & 255);
        float offx = xb[3 * HW + rem];
        float offy = xb[4 * HW + rem];
        float bw = xb[5 * HW + rem] * 4.0f;
        float bh = xb[6 * HW + rem] * 4.0f;
        float cx = (xsf + offx) * 4.0f;
        float cy = (ysf + offy) * 4.0f;
        int slot = s * TOPK + t;
        float* ob = out + (size_t)b * NBOX * 4;
        float* oc = out + (size_t)NBATCH * NBOX * 4 + b * NBOX;
        float* os = out + (size_t)NBATCH * NBOX * 5 + b * NBOX;
        ob[slot * 4 + 0] = cx - bw * 0.5f;
        ob[slot * 4 + 1] = cy - bh * 0.5f;
        ob[slot * 4 + 2] = cx + bw * 0.5f;
        ob[slot * 4 + 3] = cy + bh * 0.5f;
        float sg = 1.0f / (1.0f + expf(-z));
        os[slot] = (sg > 0.1f) ? sg : 0.0f;
        oc[slot] = (float)c;
    }
}

// ---------------------------------------------------------------------------
// Kernel 2: soft-NMS, one wave (64 threads) per batch. Decay pass is fused
// with the next round's argmax; wave-level shfl_xor reduction (no LDS tree).
// Arithmetic is verbatim from the verified kernel.
// ---------------------------------------------------------------------------
__global__ __launch_bounds__(64) void knms(float* __restrict__ out) {
    __shared__ float bxs[NBOX][4];
    __shared__ float scs[NBOX];
    __shared__ float cl[NBOX];

    const int b = blockIdx.x, t = threadIdx.x;
    float* ob  = out + (size_t)b * NBOX * 4;
    float* oc  = out + (size_t)NBATCH * NBOX * 4 + b * NBOX;
    float* os  = out + (size_t)NBATCH * NBOX * 5 + b * NBOX;
    float* okp = out + (size_t)NBATCH * NBOX * 6 + b * NBOX;

    for (int p = t; p < NBOX; p += 64) {
        bxs[p][0] = ob[p * 4 + 0];
        bxs[p][1] = ob[p * 4 + 1];
        bxs[p][2] = ob[p * 4 + 2];
        bxs[p][3] = ob[p * 4 + 3];
        scs[p] = os[p];
        cl[p]  = oc[p];
    }
    __syncthreads();

    // initial argmax over [0, NBOX): key = (score_bits << 32) | ~p
    // (scores are always >= 0, so float bits are order-preserving)
    unsigned long long local = 0ull;
    for (int p = t; p < NBOX; p += 64) {
        unsigned long long k =
            ((unsigned long long)__float_as_uint(scs[p]) << 32) | (unsigned)~(unsigned)p;
        if (k > local) local = k;
    }
    #pragma unroll
    for (int off = 32; off > 0; off >>= 1) {
        unsigned long long o = __shfl_xor(local, off);
        if (o > local) local = o;
    }
    unsigned long long kmax = local;

    for (int i = 0; i < NBOX; ++i) {
        int m = (int)(~((unsigned)kmax));           // first-occurrence max pos >= i
        if (t == 0 && m != i) {
            #pragma unroll
            for (int k = 0; k < 4; ++k) {
                float tmp = bxs[i][k]; bxs[i][k] = bxs[m][k]; bxs[m][k] = tmp;
            }
            float ts = scs[i]; scs[i] = scs[m]; scs[m] = ts;
            float tc = cl[i];  cl[i]  = cl[m];  cl[m]  = tc;
        }
        __syncthreads();

        float b0 = bxs[i][0], b1 = bxs[i][1], b2 = bxs[i][2], b3 = bxs[i][3];
        float area_i = (b2 - b0 + 1.0f) * (b3 - b1 + 1.0f);

        // fused: gaussian decay + argmax for next round (over p >= i+1)
        local = 0ull;
        for (int p = i + 1 + t; p < NBOX; p += 64) {
            float x1 = bxs[p][0], y1 = bxs[p][1], x2 = bxs[p][2], y2 = bxs[p][3];
            float areas = (x2 - x1 + 1.0f) * (y2 - y1 + 1.0f);
            float xx1 = fmaxf(b0, x1);
            float yy1 = fmaxf(b1, y1);
            float xx2 = fminf(b2, x2);
            float yy2 = fminf(b3, y2);
            float inter = fmaxf(0.0f, xx2 - xx1 + 1.0f) * fmaxf(0.0f, yy2 - yy1 + 1.0f);
            float iou = inter / (area_i + areas - inter);
            float w = expf(-(iou * iou) / 0.5f);
            float ns = w * scs[p];
            scs[p] = ns;
            unsigned long long k =
                ((unsigned long long)__float_as_uint(ns) << 32) | (unsigned)~(unsigned)p;
            if (k > local) local = k;
        }
        __syncthreads();
        #pragma unroll
        for (int off = 32; off > 0; off >>= 1) {
            unsigned long long o = __shfl_xor(local, off);
            if (o > local) local = o;
        }
        kmax = local;
    }
    __syncthreads();

    for (int p = t; p < NBOX; p += 64) {
        ob[p * 4 + 0] = bxs[p][0];
        ob[p * 4 + 1] = bxs[p][1];
        ob[p * 4 + 2] = bxs[p][2];
        ob[p * 4 + 3] = bxs[p][3];
        oc[p]  = cl[p];
        os[p]  = scs[p];
        okp[p] = (scs[p] > 0.1f) ? 1.0f : 0.0f;
    }
}

extern "C" void kernel_launch(void* const* d_in, const int* in_sizes, int n_in,
                              void* d_out, int out_size, void* d_ws, size_t ws_size,
                              hipStream_t stream) {
    const float* x = (const float*)d_in[0];
    float* out = (float*)d_out;
    ktopk<<<2 * NBATCH, 1024, 0, stream>>>(x, out);
    knms<<<NBATCH, 64, 0, stream>>>(out);
}